// Round 7
// baseline (381.435 us; speedup 1.0000x reference)
//
#include <hip/hip_runtime.h>
#include <math.h>

// Problem constants (match reference)
constexpr int N_ROWS = 100000;   // outputSize
constexpr int D      = 128;      // feature dim
constexpr int B      = 128;      // batch
constexpr int KP1    = 4097;     // K+1
constexpr int TOTAL_PAIRS = B * KP1;            // 524,416
constexpr float INV_T = 1.0f / 0.07f;
constexpr int N4 = N_ROWS * (D / 4);            // float4 per bank: 3.2M

// Bucketed CSR: 16 rows per bucket -> 6250 buckets. RPB=16 keeps LDS at
// ~17 KB/block (7 blocks/CU vs 3 at RPB=40 -> round-6 occupancy fix) and
// makes bucket math shift/mask.
constexpr int RPB  = 16;
constexpr int NB   = N_ROWS / RPB;              // 6250 (exact)
constexpr int PADR = 33;                        // float4 stride per row in LDS

// workspace layout (bytes):
//   [0)     sums: 2 floats
//   [64)    bcnt: NB ints (unpadded -- atomics serialize per word, 84/word ok)
//   [25088) bstart: NB+1 ints (+pad)
//   [50112) plist: TOTAL_PAIRS u32 (p | lr<<20 | b<<24)
constexpr size_t WS_BCNT   = 64;
constexpr size_t WS_BSTART = 25088;
constexpr size_t WS_PLIST  = 50112;
constexpr size_t WS_NEEDED = WS_PLIST + (size_t)TOTAL_PAIRS * 4;   // ~2.15 MB
constexpr size_t WS_ZERO_BYTES = WS_BSTART;                        // sums+bcnt

typedef float fvec4 __attribute__((ext_vector_type(4)));  // nontemporal-store-safe

// ---------------------------------------------------------------------------
__device__ __forceinline__ float dot4(float4 a, float4 b) {
    return a.x * b.x + a.y * b.y + a.z * b.z + a.w * b.w;
}
__device__ __forceinline__ float red32(float v) {
    #pragma unroll
    for (int off = 16; off >= 1; off >>= 1) v += __shfl_xor(v, off);
    return v;
}

// ===========================================================================
// Prep: bucket histogram -> scan -> scatter (plist packs p | lr<<20 | b<<24)
// ===========================================================================
__global__ __launch_bounds__(256) void hist_kernel(
    const int* __restrict__ idx, int* __restrict__ bcnt) {
    int stride = gridDim.x * 256;
    for (int p = blockIdx.x * 256 + threadIdx.x; p < TOTAL_PAIRS; p += stride)
        atomicAdd(&bcnt[idx[p] >> 4], 1);
}

// single block, 1024 threads x 7 bins each: exclusive scan of NB counts.
// writes bstart[0..NB]; resets bcnt[k] to the start (scatter cursor).
__global__ __launch_bounds__(1024) void scan_kernel(
    int* __restrict__ bcnt, int* __restrict__ bstart) {
    __shared__ int ssum[1024];
    const int t  = threadIdx.x;
    const int j0 = t * 7;
    int c[7];
    int local = 0;
    #pragma unroll
    for (int i = 0; i < 7; ++i) {
        c[i] = (j0 + i < NB) ? bcnt[j0 + i] : 0;
        local += c[i];
    }
    ssum[t] = local;
    __syncthreads();
    for (int off = 1; off < 1024; off <<= 1) {
        int v = (t >= off) ? ssum[t - off] : 0;
        __syncthreads();
        ssum[t] += v;
        __syncthreads();
    }
    int run = ssum[t] - local;                   // exclusive prefix
    #pragma unroll
    for (int i = 0; i < 7; ++i) {
        if (j0 + i < NB) { bstart[j0 + i] = run; bcnt[j0 + i] = run; }
        run += c[i];
    }
    if (t == 1023) bstart[NB] = ssum[1023];
}

__global__ __launch_bounds__(256) void scatter_kernel(
    const int* __restrict__ idx, int* __restrict__ bcnt,
    unsigned* __restrict__ plist) {
    int stride = gridDim.x * 256;
    for (int p = blockIdx.x * 256 + threadIdx.x; p < TOTAL_PAIRS; p += stride) {
        int r   = idx[p];
        int bkt = r >> 4;
        int lr  = r & 15;
        int b   = p / KP1;                       // magic-mul (saved in fused)
        int pos = atomicAdd(&bcnt[bkt], 1);
        plist[pos] = (unsigned)p | ((unsigned)lr << 20) | ((unsigned)b << 24);
    }
}

// ===========================================================================
// Fused: block k streams rows [k*16, k*16+16) of both banks into LDS
// (coalesced) and nt-stores them to o1/o2 (the copy rides along). Then
// 8-lane teams process the bucket's pairs: row from LDS (lane-local chunks),
// v from L1/L2 (128 B contiguous per team), 3-shuffle reduce, exp, store.
// 17 KB LDS -> 7 blocks/CU (round-6 was 42.5 KB -> 3 blocks/CU, occ 25%).
// ===========================================================================
__global__ __launch_bounds__(256) void fused_kernel(
    const float* __restrict__ v1, const float* __restrict__ v2,
    const float* __restrict__ mem1, const float* __restrict__ mem2,
    const int* __restrict__ bstart, const unsigned* __restrict__ plist,
    float* __restrict__ out, float* __restrict__ sums,
    float* __restrict__ o1, float* __restrict__ o2)
{
    __shared__ float4 sm1[RPB * PADR];   // 8,448 B
    __shared__ float4 sm2[RPB * PADR];   // 8,448 B
    __shared__ float sz1[4], sz2[4];

    const int bid = blockIdx.x;
    const int tid = threadIdx.x;
    const int r0  = bid * RPB;

    const float4* __restrict__ M1 = (const float4*)mem1;
    const float4* __restrict__ M2 = (const float4*)mem2;
    const float4* __restrict__ V1 = (const float4*)v1;
    const float4* __restrict__ V2 = (const float4*)v2;
    fvec4* __restrict__ d1 = (fvec4*)o1;
    fvec4* __restrict__ d2 = (fvec4*)o2;

    // ---- stage 16 rows (sequential, coalesced) + fused copy: 2 iters ----
    #pragma unroll
    for (int it = 0; it < 2; ++it) {
        int i  = it * 256 + tid;                 // 0..511
        int lr = i >> 5, c = i & 31;
        size_t gi = (size_t)(r0 + lr) * 32 + c;
        float4 x1 = M1[gi];
        float4 x2 = M2[gi];
        sm1[lr * PADR + c] = x1;
        sm2[lr * PADR + c] = x2;
        fvec4 y1 = {x1.x, x1.y, x1.z, x1.w};
        fvec4 y2 = {x2.x, x2.y, x2.z, x2.w};
        __builtin_nontemporal_store(y1, &d1[gi]);
        __builtin_nontemporal_store(y2, &d2[gi]);
    }
    __syncthreads();

    // ---- pair phase: 8-lane teams ----
    const int team = tid >> 3;                   // 0..31
    const int sub  = tid & 7;                    // lane within team
    const int qend = bstart[bid + 1];
    float az1 = 0.0f, az2 = 0.0f;                // x8 redundant, /8 at end

    for (int q = bstart[bid] + team; q < qend; q += 32) {
        unsigned v = plist[q];
        int p  = (int)(v & 0xFFFFFu);
        int lr = (int)((v >> 20) & 15u);
        int b  = (int)(v >> 24);

        const float4* __restrict__ w1 = &sm1[lr * PADR];
        const float4* __restrict__ w2 = &sm2[lr * PADR];
        float a = 0.0f, bb = 0.0f;
        #pragma unroll
        for (int i = 0; i < 4; ++i) {
            int c = sub + 8 * i;
            float4 vv1 = V1[b * 32 + c];
            float4 vv2 = V2[b * 32 + c];
            float4 x2  = w2[c];
            float4 x1  = w1[c];
            a  += dot4(x2, vv1);                 // out_v1 = mem2 . v1
            bb += dot4(x1, vv2);                 // out_v2 = mem1 . v2
        }
        #pragma unroll
        for (int off = 4; off >= 1; off >>= 1) {
            a  += __shfl_xor(a,  off);
            bb += __shfl_xor(bb, off);
        }
        float eA = __expf(a  * INV_T);
        float eB = __expf(bb * INV_T);
        az1 += eA;
        az2 += eB;
        if (sub < 2) out[(sub ? TOTAL_PAIRS : 0) + p] = sub ? eB : eA;
    }

    // ---- block Z reduction (x1/8 compensation) ----
    #pragma unroll
    for (int off = 32; off >= 1; off >>= 1) {
        az1 += __shfl_xor(az1, off);
        az2 += __shfl_xor(az2, off);
    }
    if ((tid & 63) == 0) { sz1[tid >> 6] = az1; sz2[tid >> 6] = az2; }
    __syncthreads();
    if (tid == 0) {
        float t1 = (sz1[0] + sz1[1] + sz1[2] + sz1[3]) * 0.125f;
        float t2 = (sz2[0] + sz2[1] + sz2[2] + sz2[3]) * 0.125f;
        atomicAdd(&sums[0], t1);
        atomicAdd(&sums[1], t2);
    }
}

// ---------------------------------------------------------------------------
// Finish: scale scores by 1/Z + overwrite y-rows of the copied banks with
// normalize(0.5*mem + 0.5*v). Stream-ordered after fused_kernel.
__global__ __launch_bounds__(256) void finish_kernel(
    float* __restrict__ out, const float* __restrict__ sums,
    const float* __restrict__ v1, const float* __restrict__ v2,
    const int* __restrict__ y,
    const float* __restrict__ mem1, const float* __restrict__ mem2,
    float* __restrict__ o1, float* __restrict__ o2)
{
    if (blockIdx.x < 2 * B && threadIdx.x < 64) {
        int b    = blockIdx.x & (B - 1);
        int bank = blockIdx.x >> 7;
        int lane = threadIdx.x;
        const float2* __restrict__ m = (const float2*)(bank ? mem2 : mem1);
        const float2* __restrict__ v = (const float2*)(bank ? v2 : v1);
        float2* __restrict__ o       = (float2*)(bank ? o2 : o1);
        int row = y[b];
        float2 mv = m[(size_t)row * 64 + lane];
        float2 vv = v[b * 64 + lane];
        float2 u;
        u.x = 0.5f * mv.x + 0.5f * vv.x;
        u.y = 0.5f * mv.y + 0.5f * vv.y;
        float ss = u.x * u.x + u.y * u.y;
        #pragma unroll
        for (int off = 32; off >= 1; off >>= 1) ss += __shfl_xor(ss, off);
        float inv = 1.0f / sqrtf(ss);
        float2 r; r.x = u.x * inv; r.y = u.y * inv;
        o[(size_t)row * 64 + lane] = r;
    }

    float sc1 = (float)((double)TOTAL_PAIRS / ((double)sums[0] * (double)N_ROWS));
    float sc2 = (float)((double)TOTAL_PAIRS / ((double)sums[1] * (double)N_ROWS));
    int stride = gridDim.x * blockDim.x;
    for (int i = blockIdx.x * blockDim.x + threadIdx.x; i < 2 * TOTAL_PAIRS;
         i += stride) {
        out[i] *= (i < TOTAL_PAIRS) ? sc1 : sc2;
    }
}

// ===========================================================================
// Fallback path (ws too small): round-3 structure.
// ===========================================================================
__global__ void init_ws_kernel(float* ws) {
    if (threadIdx.x < 2) ws[threadIdx.x] = 0.0f;
}

__global__ __launch_bounds__(256) void score_kernel(
    const float* __restrict__ v1, const float* __restrict__ v2,
    const int* __restrict__ idx,
    const float* __restrict__ mem1, const float* __restrict__ mem2,
    float* __restrict__ out, float* __restrict__ sums)
{
    __shared__ alignas(16) int s_idx[260];
    __shared__ float s1[8], s2[8];
    const int sid   = blockIdx.x;
    const int tid   = threadIdx.x;
    const int l     = tid & 31;
    const int grp   = tid >> 5;
    const int b     = sid >> 4;
    const int chunk = sid & 15;
    const int cnt   = (chunk == 15) ? 257 : 256;
    const int ibase = b * KP1 + chunk * 256;
    for (int t = tid; t < cnt; t += 256) s_idx[t] = idx[ibase + t];
    __syncthreads();
    const float4* __restrict__ m1 = (const float4*)mem1;
    const float4* __restrict__ m2 = (const float4*)mem2;
    const float4 a1 = ((const float4*)v1)[b * 32 + l];
    const float4 a2 = ((const float4*)v2)[b * 32 + l];
    const int lk = grp * 32, pbase = ibase + lk;
    float acc1 = 0.0f, acc2 = 0.0f;
    for (int u = 0; u < 32; u += 4) {
        const int4 rr = *(const int4*)&s_idx[lk + u];
        float4 wA0 = m2[(size_t)rr.x * 32 + l], wB0 = m1[(size_t)rr.x * 32 + l];
        float4 wA1 = m2[(size_t)rr.y * 32 + l], wB1 = m1[(size_t)rr.y * 32 + l];
        float4 wA2 = m2[(size_t)rr.z * 32 + l], wB2 = m1[(size_t)rr.z * 32 + l];
        float4 wA3 = m2[(size_t)rr.w * 32 + l], wB3 = m1[(size_t)rr.w * 32 + l];
        float eA0 = __expf(red32(dot4(wA0, a1)) * INV_T);
        float eB0 = __expf(red32(dot4(wB0, a2)) * INV_T);
        float eA1 = __expf(red32(dot4(wA1, a1)) * INV_T);
        float eB1 = __expf(red32(dot4(wB1, a2)) * INV_T);
        float eA2 = __expf(red32(dot4(wA2, a1)) * INV_T);
        float eB2 = __expf(red32(dot4(wB2, a2)) * INV_T);
        float eA3 = __expf(red32(dot4(wA3, a1)) * INV_T);
        float eB3 = __expf(red32(dot4(wB3, a2)) * INV_T);
        acc1 += (eA0 + eA1) + (eA2 + eA3);
        acc2 += (eB0 + eB1) + (eB2 + eB3);
        float sa = (l & 1) ? eA1 : eA0, sb = (l & 1) ? eA3 : eA2;
        float evA = (l & 2) ? sb : sa;
        float sc = (l & 1) ? eB1 : eB0, sd = (l & 1) ? eB3 : eB2;
        float evB = (l & 2) ? sd : sc;
        int p = pbase + u;
        if (l < 4)      out[p + l] = evA;
        else if (l < 8) out[TOTAL_PAIRS + p + (l - 4)] = evB;
    }
    if (chunk == 15 && grp == 7) {
        int r = s_idx[256];
        float4 wA = m2[(size_t)r * 32 + l], wB = m1[(size_t)r * 32 + l];
        float eA = __expf(red32(dot4(wA, a1)) * INV_T);
        float eB = __expf(red32(dot4(wB, a2)) * INV_T);
        acc1 += eA; acc2 += eB;
        if (l == 0) {
            out[b * KP1 + 4096] = eA;
            out[TOTAL_PAIRS + b * KP1 + 4096] = eB;
        }
    }
    if (l == 0) { s1[grp] = acc1; s2[grp] = acc2; }
    __syncthreads();
    if (tid == 0) {
        float t1 = 0.0f, t2 = 0.0f;
        #pragma unroll
        for (int i = 0; i < 8; ++i) { t1 += s1[i]; t2 += s2[i]; }
        atomicAdd(&sums[0], t1);
        atomicAdd(&sums[1], t2);
    }
}

__global__ __launch_bounds__(256) void copy_scale_kernel(
    const float* __restrict__ mem1, const float* __restrict__ mem2,
    float* __restrict__ o1, float* __restrict__ o2,
    float* __restrict__ out, const float* __restrict__ sums)
{
    const fvec4* __restrict__ m1 = (const fvec4*)mem1;
    const fvec4* __restrict__ m2 = (const fvec4*)mem2;
    fvec4* __restrict__ d1 = (fvec4*)o1;
    fvec4* __restrict__ d2 = (fvec4*)o2;
    int tid = blockIdx.x * 256 + threadIdx.x;
    int stride = gridDim.x * 256;
    for (int i = tid; i < N4; i += stride) {
        fvec4 x1 = m1[i], x2 = m2[i];
        __builtin_nontemporal_store(x1, &d1[i]);
        __builtin_nontemporal_store(x2, &d2[i]);
    }
    float sc1 = (float)((double)TOTAL_PAIRS / ((double)sums[0] * (double)N_ROWS));
    float sc2 = (float)((double)TOTAL_PAIRS / ((double)sums[1] * (double)N_ROWS));
    for (int i = tid; i < 2 * TOTAL_PAIRS; i += stride) {
        out[i] *= (i < TOTAL_PAIRS) ? sc1 : sc2;
    }
}

__global__ void rowupd_kernel(
    const float* __restrict__ v1, const float* __restrict__ v2,
    const int* __restrict__ y,
    const float* __restrict__ mem1, const float* __restrict__ mem2,
    float* __restrict__ o1, float* __restrict__ o2)
{
    int b    = blockIdx.x & (B - 1);
    int bank = blockIdx.x >> 7;
    int lane = threadIdx.x;
    const float2* __restrict__ m = (const float2*)(bank ? mem2 : mem1);
    const float2* __restrict__ v = (const float2*)(bank ? v2 : v1);
    float2* __restrict__ o       = (float2*)(bank ? o2 : o1);
    int row = y[b];
    float2 mv = m[(size_t)row * 64 + lane];
    float2 vv = v[b * 64 + lane];
    float2 u;
    u.x = 0.5f * mv.x + 0.5f * vv.x;
    u.y = 0.5f * mv.y + 0.5f * vv.y;
    float ss = u.x * u.x + u.y * u.y;
    #pragma unroll
    for (int off = 32; off >= 1; off >>= 1) ss += __shfl_xor(ss, off);
    float inv = 1.0f / sqrtf(ss);
    float2 r; r.x = u.x * inv; r.y = u.y * inv;
    o[(size_t)row * 64 + lane] = r;
}

// ---------------------------------------------------------------------------
extern "C" void kernel_launch(void* const* d_in, const int* in_sizes, int n_in,
                              void* d_out, int out_size, void* d_ws, size_t ws_size,
                              hipStream_t stream) {
    const float* v1   = (const float*)d_in[0];
    const float* v2   = (const float*)d_in[1];
    const int*   idx  = (const int*)d_in[2];
    const int*   y    = (const int*)d_in[3];
    const float* mem1 = (const float*)d_in[4];
    const float* mem2 = (const float*)d_in[5];

    float* out = (float*)d_out;
    float* out_mem1 = out + 2 * (size_t)TOTAL_PAIRS;
    float* out_mem2 = out_mem1 + (size_t)N_ROWS * D;
    char*  ws   = (char*)d_ws;
    float* sums = (float*)d_ws;

    if (ws_size >= WS_NEEDED) {
        int*      bcnt   = (int*)(ws + WS_BCNT);
        int*      bstart = (int*)(ws + WS_BSTART);
        unsigned* plist  = (unsigned*)(ws + WS_PLIST);

        hipMemsetAsync(ws, 0, WS_ZERO_BYTES, stream);
        hist_kernel<<<512, 256, 0, stream>>>(idx, bcnt);
        scan_kernel<<<1, 1024, 0, stream>>>(bcnt, bstart);
        scatter_kernel<<<512, 256, 0, stream>>>(idx, bcnt, plist);
        fused_kernel<<<NB, 256, 0, stream>>>(
            v1, v2, mem1, mem2, bstart, plist,
            out, sums, out_mem1, out_mem2);
        finish_kernel<<<1024, 256, 0, stream>>>(
            out, sums, v1, v2, y, mem1, mem2, out_mem1, out_mem2);
    } else {
        // fallback: round-3 structure (needs only 8 B of ws)
        init_ws_kernel<<<1, 64, 0, stream>>>(sums);
        score_kernel<<<2048, 256, 0, stream>>>(
            v1, v2, idx, mem1, mem2, out, sums);
        copy_scale_kernel<<<2048, 256, 0, stream>>>(
            mem1, mem2, out_mem1, out_mem2, out, sums);
        rowupd_kernel<<<2 * B, 64, 0, stream>>>(
            v1, v2, y, mem1, mem2, out_mem1, out_mem2);
    }
}

// Round 9
// 304.634 us; speedup vs baseline: 1.2521x; 1.2521x over previous
//
#include <hip/hip_runtime.h>
#include <math.h>

// Problem constants (match reference)
constexpr int N_ROWS = 100000;   // outputSize
constexpr int D      = 128;      // feature dim
constexpr int B      = 128;      // batch
constexpr int KP1    = 4097;     // K+1
constexpr int TOTAL_PAIRS = B * KP1;            // 524,416
constexpr float INV_T = 1.0f / 0.07f;
constexpr int N4 = N_ROWS * (D / 4);            // float4 per bank: 3.2M

// Bucketed CSR, fixed-capacity buckets (no hist/scan prep):
// RPB=40 rows/bucket (round-6 best fused), NB=2500 buckets,
// CAP=284 slots = mean 209.8 + 5.1 sigma; overflow -> ovf list (slow path).
constexpr int RPB  = 40;
constexpr int NB   = N_ROWS / RPB;              // 2500 (exact)
constexpr int CAP  = 284;
constexpr int PADR = 33;                        // float4 stride per row in LDS
constexpr int OVF_MAX = 4096;

// workspace layout (bytes):
//   [0)     sums: 2 floats (pad to 64)
//   [64)    bcnt: NB ints (atomic cursors; final value = bucket count)
//   [10064) ovf_cnt: 1 int
//   [10080) ovf: OVF_MAX ints (overflow pair ids)
//   [26496) plist: NB*CAP u32 (p | lr<<20)
constexpr size_t WS_BCNT   = 64;
constexpr size_t WS_OVFC   = 10064;
constexpr size_t WS_OVF    = 10080;
constexpr size_t WS_PLIST  = 26496;
constexpr size_t WS_NEEDED = WS_PLIST + (size_t)NB * CAP * 4;  // 2,866,496
constexpr size_t WS_ZERO_BYTES = WS_OVF;                       // sums+bcnt+ovf_cnt

typedef float fvec4 __attribute__((ext_vector_type(4)));  // nontemporal-store-safe

// ---------------------------------------------------------------------------
__device__ __forceinline__ float dot4(float4 a, float4 b) {
    return a.x * b.x + a.y * b.y + a.z * b.z + a.w * b.w;
}
__device__ __forceinline__ float red32(float v) {
    #pragma unroll
    for (int off = 16; off >= 1; off >>= 1) v += __shfl_xor(v, off);
    return v;
}

// ===========================================================================
// Prep: single scatter pass into fixed-capacity buckets (hist+scan removed).
// ===========================================================================
__global__ __launch_bounds__(256) void scatter_kernel(
    const int* __restrict__ idx, int* __restrict__ bcnt,
    int* __restrict__ ovfc, int* __restrict__ ovf,
    unsigned* __restrict__ plist) {
    int stride = gridDim.x * 256;
    for (int p = blockIdx.x * 256 + threadIdx.x; p < TOTAL_PAIRS; p += stride) {
        int r   = idx[p];
        int bkt = r / RPB;                       // magic-mul
        int lr  = r - bkt * RPB;
        int pos = atomicAdd(&bcnt[bkt], 1);
        if (pos < CAP) {
            plist[bkt * CAP + pos] = (unsigned)p | ((unsigned)lr << 20);
        } else {
            int o = atomicAdd(ovfc, 1);
            if (o < OVF_MAX) ovf[o] = p;
        }
    }
}

// ===========================================================================
// fused_mega: even blocks = CSR score (no stores at stage -> no vmcnt drain),
// odd blocks = streaming bank copy (nt stores). Copy waves soak HBM BW while
// score waves sit in latency stalls (round-0/2's proven concurrency trick).
// Score: stage 40 rows of both banks in LDS (padded), prefetch plist slice
// to LDS, then 8-lane teams, 2-pair unrolled (16 global + 16 LDS loads in
// flight per team iteration), 3-shuffle reduce, exp, scattered 4B stores.
// ===========================================================================
__global__ __launch_bounds__(256, 4) void fused_mega(
    const float* __restrict__ v1, const float* __restrict__ v2,
    const float* __restrict__ mem1, const float* __restrict__ mem2,
    const int* __restrict__ bcnt, const unsigned* __restrict__ plist,
    float* __restrict__ out, float* __restrict__ sums,
    float* __restrict__ o1, float* __restrict__ o2)
{
    if (blockIdx.x & 1) {
        // ---- copy half ----
        int cid = blockIdx.x >> 1;               // 0..NB-1
        const fvec4* __restrict__ m1 = (const fvec4*)mem1;
        const fvec4* __restrict__ m2 = (const fvec4*)mem2;
        fvec4* __restrict__ d1 = (fvec4*)o1;
        fvec4* __restrict__ d2 = (fvec4*)o2;
        int t = cid * 256 + threadIdx.x;
        int stride = NB * 256;
        for (int i = t; i < N4; i += stride) {
            fvec4 x1 = m1[i];
            fvec4 x2 = m2[i];
            __builtin_nontemporal_store(x1, &d1[i]);
            __builtin_nontemporal_store(x2, &d2[i]);
        }
        return;
    }

    // ---- score half ----
    __shared__ float4 sm1[RPB * PADR];           // 21,120 B
    __shared__ float4 sm2[RPB * PADR];           // 21,120 B
    __shared__ unsigned s_pl[CAP];               // 1,136 B
    __shared__ float sz1[4], sz2[4];

    const int sid = blockIdx.x >> 1;             // 0..NB-1
    const int tid = threadIdx.x;
    const int r0  = sid * RPB;

    const float4* __restrict__ M1 = (const float4*)mem1;
    const float4* __restrict__ M2 = (const float4*)mem2;
    const float4* __restrict__ V1 = (const float4*)v1;
    const float4* __restrict__ V2 = (const float4*)v2;

    // stage 40 rows x 2 banks (coalesced reads, LDS only -- no global stores)
    for (int i = tid; i < RPB * 32; i += 256) {
        int lr = i >> 5, c = i & 31;
        size_t gi = (size_t)(r0 + lr) * 32 + c;
        sm1[lr * PADR + c] = M1[gi];
        sm2[lr * PADR + c] = M2[gi];
    }
    // prefetch this bucket's plist slice (coalesced)
    int cnt = bcnt[sid];
    if (cnt > CAP) cnt = CAP;
    for (int t = tid; t < cnt; t += 256) s_pl[t] = plist[sid * CAP + t];
    __syncthreads();

    // pair phase: 8-lane teams, 2-pair unroll
    const int team = tid >> 3;                   // 0..31
    const int sub  = tid & 7;
    float az1 = 0.0f, az2 = 0.0f;                // x8 redundant, /8 at end

    for (int q = team; q < cnt; q += 64) {
        unsigned e0 = s_pl[q];
        int q1 = q + 32;
        bool have1 = (q1 < cnt);
        unsigned e1 = have1 ? s_pl[q1] : e0;

        int p0 = (int)(e0 & 0xFFFFFu), lr0 = (int)(e0 >> 20);
        int p1 = (int)(e1 & 0xFFFFFu), lr1 = (int)(e1 >> 20);
        int b0 = p0 / KP1;                       // magic-mul
        int b1 = p1 / KP1;

        const float4* __restrict__ w10 = &sm1[lr0 * PADR];
        const float4* __restrict__ w20 = &sm2[lr0 * PADR];
        const float4* __restrict__ w11 = &sm1[lr1 * PADR];
        const float4* __restrict__ w21 = &sm2[lr1 * PADR];

        float a0 = 0.0f, c0 = 0.0f, a1 = 0.0f, c1 = 0.0f;
        #pragma unroll
        for (int i = 0; i < 4; ++i) {
            int c = sub + 8 * i;
            float4 va0 = V1[b0 * 32 + c];
            float4 vb0 = V2[b0 * 32 + c];
            float4 va1 = V1[b1 * 32 + c];
            float4 vb1 = V2[b1 * 32 + c];
            float4 x20 = w20[c], x10 = w10[c];
            float4 x21 = w21[c], x11 = w11[c];
            a0 += dot4(x20, va0);                // out_v1 = mem2 . v1
            c0 += dot4(x10, vb0);                // out_v2 = mem1 . v2
            a1 += dot4(x21, va1);
            c1 += dot4(x11, vb1);
        }
        #pragma unroll
        for (int off = 4; off >= 1; off >>= 1) {
            a0 += __shfl_xor(a0, off);
            c0 += __shfl_xor(c0, off);
            a1 += __shfl_xor(a1, off);
            c1 += __shfl_xor(c1, off);
        }
        float eA0 = __expf(a0 * INV_T), eB0 = __expf(c0 * INV_T);
        float eA1 = __expf(a1 * INV_T), eB1 = __expf(c1 * INV_T);

        az1 += eA0; az2 += eB0;
        if (sub == 0) out[p0] = eA0;
        else if (sub == 1) out[TOTAL_PAIRS + p0] = eB0;
        if (have1) {
            az1 += eA1; az2 += eB1;
            if (sub == 0) out[p1] = eA1;
            else if (sub == 1) out[TOTAL_PAIRS + p1] = eB1;
        }
    }

    // block Z reduction (x1/8 compensation)
    #pragma unroll
    for (int off = 32; off >= 1; off >>= 1) {
        az1 += __shfl_xor(az1, off);
        az2 += __shfl_xor(az2, off);
    }
    if ((tid & 63) == 0) { sz1[tid >> 6] = az1; sz2[tid >> 6] = az2; }
    __syncthreads();
    if (tid == 0) {
        float t1 = (sz1[0] + sz1[1] + sz1[2] + sz1[3]) * 0.125f;
        float t2 = (sz2[0] + sz2[1] + sz2[2] + sz2[3]) * 0.125f;
        atomicAdd(&sums[0], t1);
        atomicAdd(&sums[1], t2);
    }
}

// ---------------------------------------------------------------------------
// Overflow pairs (bucket count > CAP): direct gather path. Expected ~0 calls;
// must run before finish so sums are final.
__global__ void ovf_kernel(
    const int* __restrict__ idx,
    const float* __restrict__ v1, const float* __restrict__ v2,
    const float* __restrict__ mem1, const float* __restrict__ mem2,
    const int* __restrict__ ovfc, const int* __restrict__ ovf,
    float* __restrict__ out, float* __restrict__ sums)
{
    int n = *ovfc;
    if (n > OVF_MAX) n = OVF_MAX;
    const float4* __restrict__ M1 = (const float4*)mem1;
    const float4* __restrict__ M2 = (const float4*)mem2;
    const float4* __restrict__ V1 = (const float4*)v1;
    const float4* __restrict__ V2 = (const float4*)v2;
    for (int i = threadIdx.x; i < n; i += 256) {
        int p = ovf[i];
        int r = idx[p];
        int b = p / KP1;
        float a = 0.0f, c = 0.0f;
        for (int j = 0; j < 32; ++j) {
            float4 w1 = M1[(size_t)r * 32 + j];
            float4 w2 = M2[(size_t)r * 32 + j];
            float4 x1 = V1[b * 32 + j];
            float4 x2 = V2[b * 32 + j];
            a += dot4(w2, x1);
            c += dot4(w1, x2);
        }
        float eA = __expf(a * INV_T), eB = __expf(c * INV_T);
        out[p] = eA;
        out[TOTAL_PAIRS + p] = eB;
        atomicAdd(&sums[0], eA);
        atomicAdd(&sums[1], eB);
    }
}

// ---------------------------------------------------------------------------
// Finish: scale scores by 1/Z + overwrite y-rows of the copied banks with
// normalize(0.5*mem + 0.5*v). Stream-ordered after fused_mega/ovf.
__global__ __launch_bounds__(256) void finish_kernel(
    float* __restrict__ out, const float* __restrict__ sums,
    const float* __restrict__ v1, const float* __restrict__ v2,
    const int* __restrict__ y,
    const float* __restrict__ mem1, const float* __restrict__ mem2,
    float* __restrict__ o1, float* __restrict__ o2)
{
    if (blockIdx.x < 2 * B && threadIdx.x < 64) {
        int b    = blockIdx.x & (B - 1);
        int bank = blockIdx.x >> 7;
        int lane = threadIdx.x;
        const float2* __restrict__ m = (const float2*)(bank ? mem2 : mem1);
        const float2* __restrict__ v = (const float2*)(bank ? v2 : v1);
        float2* __restrict__ o       = (float2*)(bank ? o2 : o1);
        int row = y[b];
        float2 mv = m[(size_t)row * 64 + lane];
        float2 vv = v[b * 64 + lane];
        float2 u;
        u.x = 0.5f * mv.x + 0.5f * vv.x;
        u.y = 0.5f * mv.y + 0.5f * vv.y;
        float ss = u.x * u.x + u.y * u.y;
        #pragma unroll
        for (int off = 32; off >= 1; off >>= 1) ss += __shfl_xor(ss, off);
        float inv = 1.0f / sqrtf(ss);
        float2 r; r.x = u.x * inv; r.y = u.y * inv;
        o[(size_t)row * 64 + lane] = r;
    }

    float sc1 = (float)((double)TOTAL_PAIRS / ((double)sums[0] * (double)N_ROWS));
    float sc2 = (float)((double)TOTAL_PAIRS / ((double)sums[1] * (double)N_ROWS));
    int stride = gridDim.x * blockDim.x;
    for (int i = blockIdx.x * blockDim.x + threadIdx.x; i < 2 * TOTAL_PAIRS;
         i += stride) {
        out[i] *= (i < TOTAL_PAIRS) ? sc1 : sc2;
    }
}

// ===========================================================================
// Fallback path (ws too small): round-3 structure.
// ===========================================================================
__global__ void init_ws_kernel(float* ws) {
    if (threadIdx.x < 2) ws[threadIdx.x] = 0.0f;
}

__global__ __launch_bounds__(256) void score_kernel(
    const float* __restrict__ v1, const float* __restrict__ v2,
    const int* __restrict__ idx,
    const float* __restrict__ mem1, const float* __restrict__ mem2,
    float* __restrict__ out, float* __restrict__ sums)
{
    __shared__ alignas(16) int s_idx[260];
    __shared__ float s1[8], s2[8];
    const int sid   = blockIdx.x;
    const int tid   = threadIdx.x;
    const int l     = tid & 31;
    const int grp   = tid >> 5;
    const int b     = sid >> 4;
    const int chunk = sid & 15;
    const int cnt   = (chunk == 15) ? 257 : 256;
    const int ibase = b * KP1 + chunk * 256;
    for (int t = tid; t < cnt; t += 256) s_idx[t] = idx[ibase + t];
    __syncthreads();
    const float4* __restrict__ m1 = (const float4*)mem1;
    const float4* __restrict__ m2 = (const float4*)mem2;
    const float4 a1 = ((const float4*)v1)[b * 32 + l];
    const float4 a2 = ((const float4*)v2)[b * 32 + l];
    const int lk = grp * 32, pbase = ibase + lk;
    float acc1 = 0.0f, acc2 = 0.0f;
    for (int u = 0; u < 32; u += 4) {
        const int4 rr = *(const int4*)&s_idx[lk + u];
        float4 wA0 = m2[(size_t)rr.x * 32 + l], wB0 = m1[(size_t)rr.x * 32 + l];
        float4 wA1 = m2[(size_t)rr.y * 32 + l], wB1 = m1[(size_t)rr.y * 32 + l];
        float4 wA2 = m2[(size_t)rr.z * 32 + l], wB2 = m1[(size_t)rr.z * 32 + l];
        float4 wA3 = m2[(size_t)rr.w * 32 + l], wB3 = m1[(size_t)rr.w * 32 + l];
        float eA0 = __expf(red32(dot4(wA0, a1)) * INV_T);
        float eB0 = __expf(red32(dot4(wB0, a2)) * INV_T);
        float eA1 = __expf(red32(dot4(wA1, a1)) * INV_T);
        float eB1 = __expf(red32(dot4(wB1, a2)) * INV_T);
        float eA2 = __expf(red32(dot4(wA2, a1)) * INV_T);
        float eB2 = __expf(red32(dot4(wB2, a2)) * INV_T);
        float eA3 = __expf(red32(dot4(wA3, a1)) * INV_T);
        float eB3 = __expf(red32(dot4(wB3, a2)) * INV_T);
        acc1 += (eA0 + eA1) + (eA2 + eA3);
        acc2 += (eB0 + eB1) + (eB2 + eB3);
        float sa = (l & 1) ? eA1 : eA0, sb = (l & 1) ? eA3 : eA2;
        float evA = (l & 2) ? sb : sa;
        float sc = (l & 1) ? eB1 : eB0, sd = (l & 1) ? eB3 : eB2;
        float evB = (l & 2) ? sd : sc;
        int p = pbase + u;
        if (l < 4)      out[p + l] = evA;
        else if (l < 8) out[TOTAL_PAIRS + p + (l - 4)] = evB;
    }
    if (chunk == 15 && grp == 7) {
        int r = s_idx[256];
        float4 wA = m2[(size_t)r * 32 + l], wB = m1[(size_t)r * 32 + l];
        float eA = __expf(red32(dot4(wA, a1)) * INV_T);
        float eB = __expf(red32(dot4(wB, a2)) * INV_T);
        acc1 += eA; acc2 += eB;
        if (l == 0) {
            out[b * KP1 + 4096] = eA;
            out[TOTAL_PAIRS + b * KP1 + 4096] = eB;
        }
    }
    if (l == 0) { s1[grp] = acc1; s2[grp] = acc2; }
    __syncthreads();
    if (tid == 0) {
        float t1 = 0.0f, t2 = 0.0f;
        #pragma unroll
        for (int i = 0; i < 8; ++i) { t1 += s1[i]; t2 += s2[i]; }
        atomicAdd(&sums[0], t1);
        atomicAdd(&sums[1], t2);
    }
}

__global__ __launch_bounds__(256) void copy_scale_kernel(
    const float* __restrict__ mem1, const float* __restrict__ mem2,
    float* __restrict__ o1, float* __restrict__ o2,
    float* __restrict__ out, const float* __restrict__ sums)
{
    const fvec4* __restrict__ m1 = (const fvec4*)mem1;
    const fvec4* __restrict__ m2 = (const fvec4*)mem2;
    fvec4* __restrict__ d1 = (fvec4*)o1;
    fvec4* __restrict__ d2 = (fvec4*)o2;
    int tid = blockIdx.x * 256 + threadIdx.x;
    int stride = gridDim.x * 256;
    for (int i = tid; i < N4; i += stride) {
        fvec4 x1 = m1[i], x2 = m2[i];
        __builtin_nontemporal_store(x1, &d1[i]);
        __builtin_nontemporal_store(x2, &d2[i]);
    }
    float sc1 = (float)((double)TOTAL_PAIRS / ((double)sums[0] * (double)N_ROWS));
    float sc2 = (float)((double)TOTAL_PAIRS / ((double)sums[1] * (double)N_ROWS));
    for (int i = tid; i < 2 * TOTAL_PAIRS; i += stride) {
        out[i] *= (i < TOTAL_PAIRS) ? sc1 : sc2;
    }
}

__global__ void rowupd_kernel(
    const float* __restrict__ v1, const float* __restrict__ v2,
    const int* __restrict__ y,
    const float* __restrict__ mem1, const float* __restrict__ mem2,
    float* __restrict__ o1, float* __restrict__ o2)
{
    int b    = blockIdx.x & (B - 1);
    int bank = blockIdx.x >> 7;
    int lane = threadIdx.x;
    const float2* __restrict__ m = (const float2*)(bank ? mem2 : mem1);
    const float2* __restrict__ v = (const float2*)(bank ? v2 : v1);
    float2* __restrict__ o       = (float2*)(bank ? o2 : o1);
    int row = y[b];
    float2 mv = m[(size_t)row * 64 + lane];
    float2 vv = v[b * 64 + lane];
    float2 u;
    u.x = 0.5f * mv.x + 0.5f * vv.x;
    u.y = 0.5f * mv.y + 0.5f * vv.y;
    float ss = u.x * u.x + u.y * u.y;
    #pragma unroll
    for (int off = 32; off >= 1; off >>= 1) ss += __shfl_xor(ss, off);
    float inv = 1.0f / sqrtf(ss);
    float2 r; r.x = u.x * inv; r.y = u.y * inv;
    o[(size_t)row * 64 + lane] = r;
}

// ---------------------------------------------------------------------------
extern "C" void kernel_launch(void* const* d_in, const int* in_sizes, int n_in,
                              void* d_out, int out_size, void* d_ws, size_t ws_size,
                              hipStream_t stream) {
    const float* v1   = (const float*)d_in[0];
    const float* v2   = (const float*)d_in[1];
    const int*   idx  = (const int*)d_in[2];
    const int*   y    = (const int*)d_in[3];
    const float* mem1 = (const float*)d_in[4];
    const float* mem2 = (const float*)d_in[5];

    float* out = (float*)d_out;
    float* out_mem1 = out + 2 * (size_t)TOTAL_PAIRS;
    float* out_mem2 = out_mem1 + (size_t)N_ROWS * D;
    char*  ws   = (char*)d_ws;
    float* sums = (float*)d_ws;

    if (ws_size >= WS_NEEDED) {
        int*      bcnt  = (int*)(ws + WS_BCNT);
        int*      ovfc  = (int*)(ws + WS_OVFC);
        int*      ovf   = (int*)(ws + WS_OVF);
        unsigned* plist = (unsigned*)(ws + WS_PLIST);

        hipMemsetAsync(ws, 0, WS_ZERO_BYTES, stream);
        scatter_kernel<<<512, 256, 0, stream>>>(idx, bcnt, ovfc, ovf, plist);
        fused_mega<<<2 * NB, 256, 0, stream>>>(
            v1, v2, mem1, mem2, bcnt, plist,
            out, sums, out_mem1, out_mem2);
        ovf_kernel<<<1, 256, 0, stream>>>(
            idx, v1, v2, mem1, mem2, ovfc, ovf, out, sums);
        finish_kernel<<<1024, 256, 0, stream>>>(
            out, sums, v1, v2, y, mem1, mem2, out_mem1, out_mem2);
    } else {
        // fallback: round-3 structure (needs only 8 B of ws)
        init_ws_kernel<<<1, 64, 0, stream>>>(sums);
        score_kernel<<<2048, 256, 0, stream>>>(
            v1, v2, idx, mem1, mem2, out, sums);
        copy_scale_kernel<<<2048, 256, 0, stream>>>(
            mem1, mem2, out_mem1, out_mem2, out, sums);
        rowupd_kernel<<<2 * B, 64, 0, stream>>>(
            v1, v2, y, mem1, mem2, out_mem1, out_mem2);
    }
}